// Round 1
// 175.610 us; speedup vs baseline: 1.0714x; 1.0714x over previous
//
#include <hip/hip_runtime.h>
#include <cstdint>
#include <cstddef>

// ---------------------------------------------------------------------------
// RelativePositionMultiHeadAttention, B=4 L=1024 D=1024 H=16 dk=64
// Identity: BD[...,L-1:][b,h,i,j] = Q[b,h,i] . Er[4999-j]
//  => scores = Q @ (K + Er_flip)^T / 8  -> plain softmax attention.
// R7: gemm_qkv rewritten as 256x256-tile, 8-wave, 8-phase counted-vmcnt
//     pipeline (T2 LDS XOR-swizzle + T3/T4 counted vmcnt + T5 setprio).
//     K-tiles BK=64 split into K-column halves (klo/khi, contiguous 16 KB
//     LDS blocks) so a 2-buffer schedule staggers staging vs consumption:
//       tile t phases stage (t+1,Akhi),(t+1,Bkhi),(t+2,Aklo),(t+2,Bklo);
//       vmcnt(4) once per tile => tile t+1 fully retired at its first read.
//     Region-reuse safety: (t+2,klo) overwrites tile t's klo, first write
//     issued at phase p2 (after p1's barrier, last klo read was p1);
//     (t+1,khi) overwrites tile t-1's khi (dead since t-1 p3 barrier).
// ---------------------------------------------------------------------------

typedef __attribute__((ext_vector_type(8))) short short8;   // 8 x bf16 (4 VGPR)
typedef __attribute__((ext_vector_type(4))) float f32x4;    // 4 x f32

#define MFMA_BF16(a, b, c) __builtin_amdgcn_mfma_f32_16x16x32_bf16((a), (b), (c), 0, 0, 0)

constexpr int kB = 4, kL = 1024, kD = 1024, kH = 16;
constexpr int kBL = kB * kL;   // 4096
constexpr float kScale = 0.125f * 1.44269504088896340736f;  // log2(e)/sqrt(dk)

static __device__ __forceinline__ unsigned short f32_to_bf16(float f) {
  union { float f; uint32_t u; } c; c.f = f;
  uint32_t u = c.u + 0x7fffu + ((c.u >> 16) & 1u);  // RNE
  return (unsigned short)(u >> 16);
}

static __device__ __forceinline__ void gload_lds16(const void* g, void* l) {
  __builtin_amdgcn_global_load_lds(
      (const __attribute__((address_space(1))) void*)g,
      (__attribute__((address_space(3))) void*)l, 16, 0, 0);
}

// ---------------- single fused cast: x, Wq, Wk, Wv, Wo -> bf16 ----------------
__global__ __launch_bounds__(256)
void cast_all(const float* __restrict__ x,  const float* __restrict__ Wq,
              const float* __restrict__ Wk, const float* __restrict__ Wv,
              const float* __restrict__ Wo,
              unsigned short* __restrict__ xb, unsigned short* __restrict__ Wcat,
              unsigned short* __restrict__ Wob) {
  int i = blockIdx.x * blockDim.x + threadIdx.x;
  const float* src;
  ushort4* dst;
  int off;
  if (i < 1048576) {
    src = x; dst = reinterpret_cast<ushort4*>(xb); off = i;
  } else {
    int j = i - 1048576;
    int seg = j >> 18;          // 0..3
    off = j & 262143;
    if (seg == 0)      { src = Wq; dst = reinterpret_cast<ushort4*>(Wcat); }
    else if (seg == 1) { src = Wk; dst = reinterpret_cast<ushort4*>(Wcat) + 262144; }
    else if (seg == 2) { src = Wv; dst = reinterpret_cast<ushort4*>(Wcat) + 524288; }
    else               { src = Wo; dst = reinterpret_cast<ushort4*>(Wob); }
  }
  float4 v = reinterpret_cast<const float4*>(src)[off];
  ushort4 o;
  o.x = f32_to_bf16(v.x); o.y = f32_to_bf16(v.y);
  o.z = f32_to_bf16(v.z); o.w = f32_to_bf16(v.w);
  dst[off] = o;
}

// ---------------- fused QKV GEMM  [4096 x 3072] = xb @ Wcat^T ----------------
// 256x256 tile, 8 waves (2M x 4N, wave tile 128x64), BK=64 in two K-halves.
// LDS 128 KiB: [buf][A|B][khalf] 16 KiB blocks; within a block, rows are
// packed two-per-128B line and XOR-swizzled: phys = L ^ ((line&3)<<4) where
// L = (row>>1)*128 + (row&1)*64 + colbyte  -> ds_read_b128 frag reads are
// 2-way-aliased only (free). global_load_lds writes linearly, so the inverse
// swizzle is applied to the per-lane GLOBAL source address (guide rule 21).
__global__ __launch_bounds__(512, 2)
void gemm_qkv(const unsigned short* __restrict__ A,   // 4096 x 1024 bf16
              const unsigned short* __restrict__ Bm,  // 3072 x 1024 bf16
              const float* __restrict__ bq, const float* __restrict__ bk,
              const float* __restrict__ bv,
              const float* __restrict__ Er,           // 5000x64 f32
              unsigned short* __restrict__ Qh, unsigned short* __restrict__ Kh,
              unsigned short* __restrict__ Vth) {
  __shared__ __align__(16) char smem[131072];
  const int tid  = threadIdx.x;
  const int lane = tid & 63, wave = tid >> 6;
  const int quad = lane >> 4, l15 = lane & 15, lhalf = l15 >> 1;
  const int wr = wave >> 2, wc = wave & 3;          // 2 x 4 wave grid

  // XCD-rectangular block swizzle: 8 XCDs x (4M x 6N) tile rects (192 blocks,
  // dispatcher round-robins blockIdx%8 across XCDs). Per-XCD reuse: 2MB A + 3MB B.
  const int bid = blockIdx.x;
  const int xcd = bid & 7, idx = bid >> 3;          // idx 0..23
  const int mt_ = idx / 6, nt_ = idx - mt_ * 6;
  const int m0 = ((xcd >> 1) * 4 + mt_) * 256;
  const int n0 = ((xcd & 1) * 6 + nt_) * 256;

  // swizzled ds_read lane constants: frag row = base + f*16 + l15,
  // line = row>>1, (line&3) == (l15>>1)&3 for all f (f*8 == 0 mod 4).
  const int lane_off = (l15 & 1) * 64 + ((quad * 16) ^ ((lhalf & 3) << 4));
  const int aoff = lhalf * 128 + lane_off + wr * 8192;   // + f*1024 per frag
  const int boff = lhalf * 128 + lane_off + wc * 4096;   // + n*1024 per frag

  // staging: per 16 KiB half-block, thread writes phys (j*512+tid)*16;
  // decode the logical (row, col) it must fetch (involution).
  int srow[2], scol[2];
#pragma unroll
  for (int j = 0; j < 2; ++j) {
    int poff = (j * 512 + tid) * 16;
    int L = poff ^ (((poff >> 7) & 3) << 4);
    srow[j] = ((L >> 7) << 1) | ((L >> 6) & 1);
    scol[j] = (L & 63) >> 1;                       // element index 0..31
  }

  auto stageAB = [&](int X, int kh, int tt) {      // X: 0=A 1=B, kh: 0=klo 1=khi
    const unsigned short* src = X ? Bm : A;
    const int rbase = X ? n0 : m0;
    char* dst = smem + ((tt & 1) * 65536 + X * 32768 + kh * 16384) + tid * 16;
    const int kc = tt * 64 + kh * 32;
#pragma unroll
    for (int j = 0; j < 2; ++j)
      gload_lds16(src + (size_t)(rbase + srow[j]) * 1024 + kc + scol[j],
                  dst + j * 8192);
  };

  const f32x4 vzero = {0.f, 0.f, 0.f, 0.f};
  f32x4 acc[8][4];
#pragma unroll
  for (int i = 0; i < 8; ++i)
#pragma unroll
    for (int j = 0; j < 4; ++j) acc[i][j] = vzero;

  // ---- prologue: tile0 all 4 halves + tile1 klo; vmcnt(4) retires tile0 ----
  stageAB(0, 0, 0); stageAB(1, 0, 0); stageAB(0, 1, 0); stageAB(1, 1, 0);
  stageAB(0, 0, 1); stageAB(1, 0, 1);
  asm volatile("s_waitcnt vmcnt(4)" ::: "memory");
  __builtin_amdgcn_s_barrier();

#define LDA(KH, MB) do {                                                      \
    _Pragma("unroll")                                                         \
    for (int f_ = 0; f_ < 4; ++f_)                                            \
      af[f_] = *(const short8*)(RA + (KH) * 16384 + aoff + ((MB) + f_) * 1024); \
  } while (0)
#define LDB(KH) do {                                                          \
    _Pragma("unroll")                                                         \
    for (int n_ = 0; n_ < 4; ++n_)                                            \
      bf[n_] = *(const short8*)(RB + (KH) * 16384 + boff + n_ * 1024);        \
  } while (0)
#define BARA() do {                                                           \
    __builtin_amdgcn_s_barrier();                                             \
    asm volatile("s_waitcnt lgkmcnt(0)" ::: "memory");                        \
    __builtin_amdgcn_sched_barrier(0);                                        \
  } while (0)
#define MFMA_QUAD(MB) do {                                                    \
    __builtin_amdgcn_s_setprio(1);                                            \
    _Pragma("unroll")                                                         \
    for (int mq_ = 0; mq_ < 4; ++mq_) {                                       \
      _Pragma("unroll")                                                       \
      for (int nq_ = 0; nq_ < 4; ++nq_)                                       \
        acc[(MB) + mq_][nq_] =                                                \
            MFMA_BF16(af[mq_], bf[nq_], acc[(MB) + mq_][nq_]);                \
    }                                                                         \
    __builtin_amdgcn_s_setprio(0);                                            \
  } while (0)

  for (int t = 0; t < 16; ++t) {
    const char* RA = smem + (t & 1) * 65536;
    const char* RB = RA + 32768;
    short8 af[4], bf[4];
    // p0: klo, frag-rows 0-3 (+ B klo); stage (t+1, A khi)
    LDA(0, 0); LDB(0);
    if (t + 1 < 16) stageAB(0, 1, t + 1);
    BARA(); MFMA_QUAD(0);
    __builtin_amdgcn_s_barrier();
    // p1: klo, frag-rows 4-7 (B reused); stage (t+1, B khi)
    LDA(0, 4);
    if (t + 1 < 16) stageAB(1, 1, t + 1);
    BARA(); MFMA_QUAD(4);
    __builtin_amdgcn_s_barrier();
    // p2: khi, frag-rows 0-3 (+ B khi); stage (t+2, A klo)
    LDA(1, 0); LDB(1);
    if (t + 2 < 16) stageAB(0, 0, t + 2);
    BARA(); MFMA_QUAD(0);
    __builtin_amdgcn_s_barrier();
    // p3: khi, frag-rows 4-7; stage (t+2, B klo); counted vmcnt, barrier
    LDA(1, 4);
    if (t + 2 < 16) stageAB(1, 0, t + 2);
    BARA(); MFMA_QUAD(4);
    if (t < 14) asm volatile("s_waitcnt vmcnt(4)" ::: "memory");
    else        asm volatile("s_waitcnt vmcnt(0)" ::: "memory");
    __builtin_amdgcn_s_barrier();
  }

#undef LDA
#undef LDB
#undef BARA
#undef MFMA_QUAD

  // ---- epilogue: wave tile 128x64 at (m0+wr*128, n0+wc*64) ----
  const int wsel = n0 >> 10;                 // 0=Q 1=K 2=V (block-uniform)
  const int gmb  = m0 + wr * 128;
  const int bb   = gmb >> 10, i0l = gmb & 1023;
  const int nl0  = (n0 & 1023) + wc * 64;    // 64-aligned: single head per wave
  const int hh   = nl0 >> 6;
  const size_t bh = (size_t)(bb * 16 + hh);

  if (wsel == 0) {
#pragma unroll
    for (int mf = 0; mf < 8; ++mf)
#pragma unroll
      for (int nf = 0; nf < 4; ++nf)
#pragma unroll
        for (int r = 0; r < 4; ++r) {
          const int i = i0l + mf * 16 + quad * 4 + r;
          const int n = nl0 + nf * 16 + l15;
          float v = (acc[mf][nf][r] + bq[n]) * kScale;  // fold softmax scale
          Qh[(bh * 1024 + i) * 64 + (n & 63)] = f32_to_bf16(v);
        }
  } else if (wsel == 1) {
#pragma unroll
    for (int mf = 0; mf < 8; ++mf)
#pragma unroll
      for (int nf = 0; nf < 4; ++nf)
#pragma unroll
        for (int r = 0; r < 4; ++r) {
          const int i = i0l + mf * 16 + quad * 4 + r;
          const int n = nl0 + nf * 16 + l15;
          const int d = n & 63;
          float v = acc[mf][nf][r] + bk[n] + Er[(size_t)(4999 - i) * 64 + d];
          Kh[(bh * 1024 + i) * 64 + d] = f32_to_bf16(v);
        }
  } else {
    // V: transpose 128x64 wave subtile through wave-private 16 KiB of LDS.
    __syncthreads();                         // all waves past final barrier
    unsigned short* W = (unsigned short*)smem + (size_t)wave * 8192;  // 64x128
#pragma unroll
    for (int mf = 0; mf < 8; ++mf)
#pragma unroll
      for (int nf = 0; nf < 4; ++nf) {
        ushort4 pk;
        const int n = nl0 + nf * 16 + l15;
        pk.x = f32_to_bf16(acc[mf][nf][0] + bv[n]);
        pk.y = f32_to_bf16(acc[mf][nf][1] + bv[n]);
        pk.z = f32_to_bf16(acc[mf][nf][2] + bv[n]);
        pk.w = f32_to_bf16(acc[mf][nf][3] + bv[n]);
        // W[d][i]: d = nf*16+l15, i = mf*16+quad*4+(0..3) (one-time conflicts OK)
        *(ushort4*)&W[(size_t)(nf * 16 + l15) * 128 + mf * 16 + quad * 4] = pk;
      }
    // wave-private region: compiler inserts lgkmcnt wait before re-read
#pragma unroll
    for (int p = 0; p < 16; ++p) {
      const int u = p * 64 + lane;           // 1024 x 16B units, wave-local
      const int d = u >> 4, ch = (u & 15) * 8;
      short8 vv = *(const short8*)&W[(size_t)d * 128 + ch];
      *(short8*)&Vth[(bh * 64 + d) * 1024 + i0l + ch] = vv;
    }
  }
}

// ---------------- out GEMM  out[4096,1024] = Aoh @ Wo^T + b_o ----------------
// 128x64 tile, BK=64 two-plane -> 512 blocks. 4 waves stacked in M.
__global__ __launch_bounds__(256)
void gemm_out(const unsigned short* __restrict__ A,   // 4096 x 1024
              const unsigned short* __restrict__ Bm,  // 1024 x 1024
              const float* __restrict__ bias,
              float* __restrict__ outf) {
  __shared__ unsigned short As[2][128 * 32];  // 16 KB
  __shared__ unsigned short Bs[2][64 * 32];   // 8 KB
  const int tid  = threadIdx.x;
  const int lane = tid & 63, wave = tid >> 6;
  const int quad = lane >> 4, l15 = lane & 15;
  const int m0 = blockIdx.y * 128, n0 = blockIdx.x * 64;
  const int K = 1024;

  const f32x4 vzero = {0.f, 0.f, 0.f, 0.f};
  f32x4 acc[2][4];
#pragma unroll
  for (int i = 0; i < 2; ++i)
#pragma unroll
    for (int j = 0; j < 4; ++j) acc[i][j] = vzero;

  for (int k0 = 0; k0 < K; k0 += 64) {
    __syncthreads();
#pragma unroll
    for (int j = 0; j < 4; ++j) {       // A: 1024 units
      int u = j * 256 + tid;
      int half = u >> 9, row = (u >> 2) & 127, c = (u & 3) * 8 + half * 32;
      gload_lds16(A + (size_t)(m0 + row) * K + k0 + c, (char*)&As[0][0] + (size_t)u * 16);
    }
#pragma unroll
    for (int j = 0; j < 2; ++j) {       // B: 512 units
      int u = j * 256 + tid;
      int half = u >> 8, row = (u >> 2) & 63, c = (u & 3) * 8 + half * 32;
      gload_lds16(Bm + (size_t)(n0 + row) * K + k0 + c, (char*)&Bs[0][0] + (size_t)u * 16);
    }
    __syncthreads();

#pragma unroll
    for (int ks = 0; ks < 2; ++ks) {
      short8 af[2], bfv[4];
#pragma unroll
      for (int mt = 0; mt < 2; ++mt)
        af[mt] = *(const short8*)&As[ks][(wave * 32 + mt * 16 + l15) * 32 + quad * 8];
#pragma unroll
      for (int nt = 0; nt < 4; ++nt)
        bfv[nt] = *(const short8*)&Bs[ks][(nt * 16 + l15) * 32 + quad * 8];
#pragma unroll
      for (int mt = 0; mt < 2; ++mt)
#pragma unroll
        for (int nt = 0; nt < 4; ++nt)
          acc[mt][nt] = MFMA_BF16(af[mt], bfv[nt], acc[mt][nt]);
    }
  }

#pragma unroll
  for (int mt = 0; mt < 2; ++mt)
#pragma unroll
    for (int nt = 0; nt < 4; ++nt)
#pragma unroll
      for (int r = 0; r < 4; ++r) {
        const int gm = m0 + wave * 32 + mt * 16 + quad * 4 + r;
        const int gn = n0 + nt * 16 + l15;
        outf[(size_t)gm * 1024 + gn] = acc[mt][nt][r] + bias[gn];
      }
}

// ---------------- flash attention, LDS-staged K/V, prefetch ----------------
// grid (64 bh, 8 qblocks of 128), 256 threads. Wave owns 32 query rows.
// Q pre-scaled by log2(e)/8; no-max softmax (exp2 cannot overflow here).
__global__ __launch_bounds__(256)
void attn_kernel(const unsigned short* __restrict__ Q,
                 const unsigned short* __restrict__ Kp,
                 const unsigned short* __restrict__ Vt,
                 unsigned short* __restrict__ Ao) {
  __shared__ unsigned short Ks[2][2][64 * 32];  // [buf][half][key][32]
  __shared__ unsigned short Vs[2][2][64 * 32];  // [buf][half][d][32]
  __shared__ unsigned short Plds[4][32 * 72];   // per-wave P transpose
  const int tid  = threadIdx.x;
  const int lane = tid & 63, wave = tid >> 6;
  const int quad = lane >> 4, l15 = lane & 15;
  const int bh = blockIdx.x;
  const int qb = blockIdx.y;
  const size_t base  = (size_t)bh * (kL * 64);
  const size_t vbase = (size_t)bh * (64 * kL);
  const int i0 = qb * 128 + wave * 32;

  short8 qf[2][2];
#pragma unroll
  for (int mt = 0; mt < 2; ++mt)
#pragma unroll
    for (int ks = 0; ks < 2; ++ks)
      qf[mt][ks] = *(const short8*)
          &Q[base + (size_t)(i0 + mt * 16 + l15) * 64 + ks * 32 + quad * 8];

  auto stage = [&](int buf, int kb) {
#pragma unroll
    for (int j = 0; j < 2; ++j) {
      int u = j * 256 + tid;
      int half = u >> 8, row = (u >> 2) & 63, c = (u & 3) * 8;
      gload_lds16(Kp + base + (size_t)(kb * 64 + row) * 64 + half * 32 + c,
                  (char*)&Ks[buf][0][0] + (size_t)u * 16);
      gload_lds16(Vt + vbase + (size_t)row * kL + kb * 64 + half * 32 + c,
                  (char*)&Vs[buf][0][0] + (size_t)u * 16);
    }
  };

  const f32x4 vzero = {0.f, 0.f, 0.f, 0.f};
  f32x4 of[2][4];
#pragma unroll
  for (int mt = 0; mt < 2; ++mt)
#pragma unroll
    for (int dt = 0; dt < 4; ++dt) of[mt][dt] = vzero;
  float lsum[2][4] = {{0.f, 0.f, 0.f, 0.f}, {0.f, 0.f, 0.f, 0.f}};

  unsigned short* Pw = Plds[wave];

  stage(0, 0);
  __syncthreads();

  for (int kb = 0; kb < 16; ++kb) {
    const int cur = kb & 1, nxt = cur ^ 1;
    if (kb < 15) stage(nxt, kb + 1);

    short8 kf[4][2];
#pragma unroll
    for (int nt = 0; nt < 4; ++nt)
#pragma unroll
      for (int ks = 0; ks < 2; ++ks)
        kf[nt][ks] = *(const short8*)&Ks[cur][ks][(nt * 16 + l15) * 32 + quad * 8];
    f32x4 sf[2][4];
#pragma unroll
    for (int mt = 0; mt < 2; ++mt)
#pragma unroll
      for (int nt = 0; nt < 4; ++nt) {
        sf[mt][nt] = MFMA_BF16(qf[mt][0], kf[nt][0], vzero);
        sf[mt][nt] = MFMA_BF16(qf[mt][1], kf[nt][1], sf[mt][nt]);
      }

#pragma unroll
    for (int mt = 0; mt < 2; ++mt)
#pragma unroll
      for (int nt = 0; nt < 4; ++nt)
#pragma unroll
        for (int r = 0; r < 4; ++r) {
          float p = __builtin_amdgcn_exp2f(sf[mt][nt][r]);
          lsum[mt][r] += p;
          union { float f; uint32_t u; } c; c.f = p;
          Pw[(mt * 16 + quad * 4 + r) * 72 + nt * 16 + l15] =
              (unsigned short)((c.u + 0x8000u) >> 16);
        }
    short8 pf[2][2];
#pragma unroll
    for (int mt = 0; mt < 2; ++mt)
#pragma unroll
      for (int ks = 0; ks < 2; ++ks)
        pf[mt][ks] = *(const short8*)&Pw[(mt * 16 + l15) * 72 + ks * 32 + quad * 8];

    short8 vf[4][2];
#pragma unroll
    for (int dt = 0; dt < 4; ++dt)
#pragma unroll
      for (int ks = 0; ks < 2; ++ks)
        vf[dt][ks] = *(const short8*)&Vs[cur][ks][(dt * 16 + l15) * 32 + quad * 8];
#pragma unroll
    for (int mt = 0; mt < 2; ++mt)
#pragma unroll
      for (int dt = 0; dt < 4; ++dt) {
        of[mt][dt] = MFMA_BF16(pf[mt][0], vf[dt][0], of[mt][dt]);
        of[mt][dt] = MFMA_BF16(pf[mt][1], vf[dt][1], of[mt][dt]);
      }

    __syncthreads();
  }

#pragma unroll
  for (int mask = 1; mask < 16; mask <<= 1)
#pragma unroll
    for (int mt = 0; mt < 2; ++mt)
#pragma unroll
      for (int r = 0; r < 4; ++r)
        lsum[mt][r] += __shfl_xor(lsum[mt][r], mask);
  float rl[2][4];
#pragma unroll
  for (int mt = 0; mt < 2; ++mt)
#pragma unroll
    for (int r = 0; r < 4; ++r) rl[mt][r] = __builtin_amdgcn_rcpf(lsum[mt][r]);

  const int b = bh >> 4, h = bh & 15;
#pragma unroll
  for (int mt = 0; mt < 2; ++mt)
#pragma unroll
    for (int dt = 0; dt < 4; ++dt)
#pragma unroll
      for (int r = 0; r < 4; ++r) {
        const int ig = i0 + mt * 16 + quad * 4 + r;
        float v = of[mt][dt][r] * rl[mt][r];
        Ao[((size_t)(b * 1024 + ig)) * 1024 + h * 64 + dt * 16 + l15] = f32_to_bf16(v);
      }
}

// ---------------------------------------------------------------------------
extern "C" void kernel_launch(void* const* d_in, const int* in_sizes, int n_in,
                              void* d_out, int out_size, void* d_ws, size_t ws_size,
                              hipStream_t stream) {
  const float* x   = (const float*)d_in[0];
  const float* W_q = (const float*)d_in[1];
  const float* b_q = (const float*)d_in[2];
  const float* W_k = (const float*)d_in[3];
  const float* b_k = (const float*)d_in[4];
  const float* W_v = (const float*)d_in[5];
  const float* b_v = (const float*)d_in[6];
  const float* W_o = (const float*)d_in[7];
  const float* b_o = (const float*)d_in[8];
  const float* Er  = (const float*)d_in[9];
  float* out = (float*)d_out;

  char* ws = (char*)d_ws;
  unsigned short* xb   = (unsigned short*)(ws + (size_t)0);          // 8 MB
  unsigned short* Wcat = (unsigned short*)(ws + ((size_t)8  << 20)); // 6 MB (Wq|Wk|Wv)
  unsigned short* Wob  = (unsigned short*)(ws + ((size_t)14 << 20)); // 2 MB
  unsigned short* Qh   = (unsigned short*)(ws + ((size_t)16 << 20)); // 8 MB [bh][i][d]
  unsigned short* Kh   = (unsigned short*)(ws + ((size_t)24 << 20)); // 8 MB [bh][i][d]
  unsigned short* Vth  = (unsigned short*)(ws + ((size_t)32 << 20)); // 8 MB [bh][d][i]
  unsigned short* Aoh  = (unsigned short*)(ws + ((size_t)40 << 20)); // 8 MB [b*L][D]

  cast_all<<<8192, 256, 0, stream>>>(x, W_q, W_k, W_v, W_o, xb, Wcat, Wob);

  gemm_qkv<<<192, 512, 0, stream>>>(
      xb, Wcat, b_q, b_k, b_v, Er, Qh, Kh, Vth);

  attn_kernel<<<dim3(kB * kH, kL / 128), 256, 0, stream>>>(Qh, Kh, Vth, Aoh);

  gemm_out<<<dim3(16, 32), 256, 0, stream>>>(Aoh, Wob, b_o, out);
}

// Round 2
// 173.354 us; speedup vs baseline: 1.0853x; 1.0130x over previous
//
#include <hip/hip_runtime.h>
#include <cstdint>
#include <cstddef>

// ---------------------------------------------------------------------------
// RelativePositionMultiHeadAttention, B=4 L=1024 D=1024 H=16 dk=64
// Identity: BD[...,L-1:][b,h,i,j] = Q[b,h,i] . Er[4999-j]
//  => scores = Q @ (K + Er_flip)^T / 8  -> plain softmax attention.
// R8: gemm_qkv re-tiled 256x192 -> grid 16x16 = 256 blocks (1/CU, full
//     machine; R7's 192-block grid idled 25% of CUs). Two counted vmcnt
//     waits per K-tile (end-p1: vmcnt(7) retires Akhi(t); end-p3: vmcnt(4)
//     retires Aklo(t+1)+B(t+1)) so every staged load has >=4 phases of
//     latency cover (R7's single per-tile wait gave khi only 2-3 phases).
//     B is a single [192][64] swizzled plane (3x16B/thread staging, uniform
//     ledger); A keeps the khalf-split 2-rows-per-line swizzle. Epilogue is
//     per-16-col-frag (192 tiles straddle Q/K/V boundaries).
// ---------------------------------------------------------------------------

typedef __attribute__((ext_vector_type(8))) short short8;   // 8 x bf16 (4 VGPR)
typedef __attribute__((ext_vector_type(4))) float f32x4;    // 4 x f32

#define MFMA_BF16(a, b, c) __builtin_amdgcn_mfma_f32_16x16x32_bf16((a), (b), (c), 0, 0, 0)

constexpr int kB = 4, kL = 1024, kD = 1024, kH = 16;
constexpr int kBL = kB * kL;   // 4096
constexpr float kScale = 0.125f * 1.44269504088896340736f;  // log2(e)/sqrt(dk)

static __device__ __forceinline__ unsigned short f32_to_bf16(float f) {
  union { float f; uint32_t u; } c; c.f = f;
  uint32_t u = c.u + 0x7fffu + ((c.u >> 16) & 1u);  // RNE
  return (unsigned short)(u >> 16);
}

static __device__ __forceinline__ void gload_lds16(const void* g, void* l) {
  __builtin_amdgcn_global_load_lds(
      (const __attribute__((address_space(1))) void*)g,
      (__attribute__((address_space(3))) void*)l, 16, 0, 0);
}

// ---------------- single fused cast: x, Wq, Wk, Wv, Wo -> bf16 ----------------
__global__ __launch_bounds__(256)
void cast_all(const float* __restrict__ x,  const float* __restrict__ Wq,
              const float* __restrict__ Wk, const float* __restrict__ Wv,
              const float* __restrict__ Wo,
              unsigned short* __restrict__ xb, unsigned short* __restrict__ Wcat,
              unsigned short* __restrict__ Wob) {
  int i = blockIdx.x * blockDim.x + threadIdx.x;
  const float* src;
  ushort4* dst;
  int off;
  if (i < 1048576) {
    src = x; dst = reinterpret_cast<ushort4*>(xb); off = i;
  } else {
    int j = i - 1048576;
    int seg = j >> 18;          // 0..3
    off = j & 262143;
    if (seg == 0)      { src = Wq; dst = reinterpret_cast<ushort4*>(Wcat); }
    else if (seg == 1) { src = Wk; dst = reinterpret_cast<ushort4*>(Wcat) + 262144; }
    else if (seg == 2) { src = Wv; dst = reinterpret_cast<ushort4*>(Wcat) + 524288; }
    else               { src = Wo; dst = reinterpret_cast<ushort4*>(Wob); }
  }
  float4 v = reinterpret_cast<const float4*>(src)[off];
  ushort4 o;
  o.x = f32_to_bf16(v.x); o.y = f32_to_bf16(v.y);
  o.z = f32_to_bf16(v.z); o.w = f32_to_bf16(v.w);
  dst[off] = o;
}

// ---------------- fused QKV GEMM  [4096 x 3072] = xb @ Wcat^T ----------------
// 256x192 tile, 8 waves (2M x 4N, wave tile 128x48), BK=64 in two K-halves
// for A; B staged whole-tile. LDS 112 KiB:
//   A: [buf][khalf][256][32] 2B  (16 KiB half-blocks, 2-rows-per-128B-line,
//      byte ^= (line&3)<<4 swizzle)           offsets 0..65535
//   B: [buf][192][64] 2B  (row-per-128B-line, byte ^= (row&7)<<4 swizzle)
//                                              offsets 65536..114687
// Stage ledger (uniform per thread: A-half=2 loads, B=3):
//   tile t: p0 stage B(t+1); p1 stage Akhi(t+1); p2 stage Aklo(t+2).
//   end-p1: vmcnt(7) retires Akhi(t) (issued p1 of t-1, 4 phases cover);
//   end-p3: vmcnt(4) retires Aklo(t+1) (p2 of t-1) + B(t+1) (p0 of t).
__global__ __launch_bounds__(512, 2)
void gemm_qkv(const unsigned short* __restrict__ A,   // 4096 x 1024 bf16
              const unsigned short* __restrict__ Bm,  // 3072 x 1024 bf16
              const float* __restrict__ bq, const float* __restrict__ bk,
              const float* __restrict__ bv,
              const float* __restrict__ Er,           // 5000x64 f32
              unsigned short* __restrict__ Qh, unsigned short* __restrict__ Kh,
              unsigned short* __restrict__ Vth) {
  __shared__ __align__(16) char smem[114688];
  const int tid  = threadIdx.x;
  const int lane = tid & 63, wave = tid >> 6;
  const int quad = lane >> 4, l15 = lane & 15;
  const int wr = wave >> 2, wc = wave & 3;          // 2 x 4 wave grid

  // XCD swizzle: 256 blocks, 32/XCD; per-XCD rect 4M x 8N.
  const int bid = blockIdx.x;
  const int xcd = bid & 7, idx = bid >> 3;          // idx 0..31
  const int m0 = ((xcd >> 1) * 4 + (idx >> 3)) * 256;
  const int n0 = ((xcd & 1) * 8 + (idx & 7)) * 192;

  // A ds_read lane constants (frag row = wr*128 + mf*16 + l15):
  const int aoff = (l15 >> 1) * 128 + (l15 & 1) * 64 +
                   ((quad * 16) ^ (((l15 >> 1) & 3) << 4)) + wr * 8192;
  // B ds_read lane constants (frag row = wc*48 + nf*16 + l15; row&7 == l15&7):
  const int b_lane = (quad * 16) ^ ((l15 & 7) << 4);
  const int boff = (wc * 48 + l15) * 128 + b_lane;   // + nf*2048, ^ kh*64

  // staging decoders (phys -> logical, involutions)
  int srowA[2], scolA[2];
#pragma unroll
  for (int j = 0; j < 2; ++j) {
    int poff = (j * 512 + tid) * 16;
    int L = poff ^ (((poff >> 7) & 3) << 4);
    srowA[j] = ((L >> 7) << 1) | ((L >> 6) & 1);
    scolA[j] = (L & 63) >> 1;                        // elem 0..31
  }
  int srowB[3], scolB[3];
#pragma unroll
  for (int j = 0; j < 3; ++j) {
    int poff = (j * 512 + tid) * 16;
    int L = poff ^ (((poff >> 7) & 7) << 4);
    srowB[j] = L >> 7;                               // 0..191
    scolB[j] = (L & 127) >> 1;                       // elem 0..63
  }

  auto stageA = [&](int kh, int tt) {                // 2 loads/thread
    char* dst = smem + (tt & 1) * 32768 + kh * 16384 + tid * 16;
    const int kc = tt * 64 + kh * 32;
#pragma unroll
    for (int j = 0; j < 2; ++j)
      gload_lds16(A + (size_t)(m0 + srowA[j]) * 1024 + kc + scolA[j],
                  dst + j * 8192);
  };
  auto stageB = [&](int tt) {                        // 3 loads/thread
    char* dst = smem + 65536 + (tt & 1) * 24576 + tid * 16;
    const int kc = tt * 64;
#pragma unroll
    for (int j = 0; j < 3; ++j)
      gload_lds16(Bm + (size_t)(n0 + srowB[j]) * 1024 + kc + scolB[j],
                  dst + j * 8192);
  };

  const f32x4 vzero = {0.f, 0.f, 0.f, 0.f};
  f32x4 acc[8][3];
#pragma unroll
  for (int i = 0; i < 8; ++i)
#pragma unroll
    for (int j = 0; j < 3; ++j) acc[i][j] = vzero;

  // ---- prologue: queue order [Aklo(0), B(0) | Akhi(0), Aklo(1)] ----
  stageA(0, 0); stageB(0); stageA(1, 0); stageA(0, 1);
  asm volatile("s_waitcnt vmcnt(4)" ::: "memory");
  __builtin_amdgcn_s_barrier();

#define LDA(KH, MB) do {                                                      \
    _Pragma("unroll")                                                         \
    for (int f_ = 0; f_ < 4; ++f_)                                            \
      af[f_] = *(const short8*)(RA + (KH) * 16384 + aoff + ((MB) + f_) * 1024); \
  } while (0)
#define LDB(KH) do {                                                          \
    _Pragma("unroll")                                                         \
    for (int n_ = 0; n_ < 3; ++n_)                                            \
      bf[n_] = *(const short8*)(RB + ((boff + n_ * 2048) ^ ((KH) * 64)));     \
  } while (0)
#define BARA() do {                                                           \
    __builtin_amdgcn_s_barrier();                                             \
    asm volatile("s_waitcnt lgkmcnt(0)" ::: "memory");                        \
    __builtin_amdgcn_sched_barrier(0);                                        \
  } while (0)
#define MFMA_12(MB) do {                                                      \
    __builtin_amdgcn_s_setprio(1);                                            \
    _Pragma("unroll")                                                         \
    for (int mq_ = 0; mq_ < 4; ++mq_) {                                       \
      _Pragma("unroll")                                                       \
      for (int nq_ = 0; nq_ < 3; ++nq_)                                       \
        acc[(MB) + mq_][nq_] =                                                \
            MFMA_BF16(af[mq_], bf[nq_], acc[(MB) + mq_][nq_]);                \
    }                                                                         \
    __builtin_amdgcn_s_setprio(0);                                            \
  } while (0)

  for (int t = 0; t < 16; ++t) {
    const char* RA = smem + (t & 1) * 32768;
    const char* RB = smem + 65536 + (t & 1) * 24576;
    short8 af[4], bf[3];
    // p0: klo, M-half 0 (+ B klo); stage B(t+1)
    LDA(0, 0); LDB(0);
    if (t + 1 < 16) stageB(t + 1);
    BARA(); MFMA_12(0);
    __builtin_amdgcn_s_barrier();
    // p1: klo, M-half 1 (B reused); stage Akhi(t+1); counted wait for khi(t)
    LDA(0, 4);
    if (t + 1 < 16) stageA(1, t + 1);
    BARA(); MFMA_12(4);
    if (t < 15) asm volatile("s_waitcnt vmcnt(7)" ::: "memory");
    else        asm volatile("s_waitcnt vmcnt(0)" ::: "memory");
    __builtin_amdgcn_s_barrier();
    // p2: khi, M-half 0 (+ B khi); stage Aklo(t+2)
    LDA(1, 0); LDB(1);
    if (t + 2 < 16) stageA(0, t + 2);
    BARA(); MFMA_12(0);
    __builtin_amdgcn_s_barrier();
    // p3: khi, M-half 1; counted wait for klo(t+1)+B(t+1)
    LDA(1, 4);
    BARA(); MFMA_12(4);
    if (t < 14)       asm volatile("s_waitcnt vmcnt(4)" ::: "memory");
    else if (t == 14) asm volatile("s_waitcnt vmcnt(2)" ::: "memory");
    else              asm volatile("s_waitcnt vmcnt(0)" ::: "memory");
    __builtin_amdgcn_s_barrier();
  }

#undef LDA
#undef LDB
#undef BARA
#undef MFMA_12

  // ---- epilogue: per-16-col-frag dispatch (wsel uniform per frag) ----
  __syncthreads();                           // before LDS arena reuse (uncond.)
  const int gmb = m0 + wr * 128;
  const int bb  = gmb >> 10, i0l = gmb & 1023;
  unsigned short* Wv = (unsigned short*)smem + (size_t)wave * 6144;  // 12 KiB

#pragma unroll
  for (int nf = 0; nf < 3; ++nf) {
    const int n    = n0 + wc * 48 + nf * 16;  // 16-aligned global col
    const int wsel = n >> 10;                 // 0=Q 1=K 2=V
    const int nin  = n & 1023;
    const int hh   = nin >> 6, d0 = nin & 63; // d0 in {0,16,32,48}
    const size_t bh = (size_t)(bb * 16 + hh);

    if (wsel == 0) {
#pragma unroll
      for (int mf = 0; mf < 8; ++mf)
#pragma unroll
        for (int r = 0; r < 4; ++r) {
          const int i = i0l + mf * 16 + quad * 4 + r;
          float v = (acc[mf][nf][r] + bq[nin + l15]) * kScale;  // fold scale
          Qh[(bh * 1024 + i) * 64 + d0 + l15] = f32_to_bf16(v);
        }
    } else if (wsel == 1) {
#pragma unroll
      for (int mf = 0; mf < 8; ++mf)
#pragma unroll
        for (int r = 0; r < 4; ++r) {
          const int i = i0l + mf * 16 + quad * 4 + r;
          float v = acc[mf][nf][r] + bk[nin + l15] +
                    Er[(size_t)(4999 - i) * 64 + d0 + l15];
          Kh[(bh * 1024 + i) * 64 + d0 + l15] = f32_to_bf16(v);
        }
    } else {
      // V: transpose 16(d) x 128(i) through wave-private LDS sub-region.
      unsigned short* Wn = Wv + nf * 2048;    // [16][128]
#pragma unroll
      for (int mf = 0; mf < 8; ++mf) {
        ushort4 pk;
        pk.x = f32_to_bf16(acc[mf][nf][0] + bv[nin + l15]);
        pk.y = f32_to_bf16(acc[mf][nf][1] + bv[nin + l15]);
        pk.z = f32_to_bf16(acc[mf][nf][2] + bv[nin + l15]);
        pk.w = f32_to_bf16(acc[mf][nf][3] + bv[nin + l15]);
        *(ushort4*)&Wn[(size_t)l15 * 128 + mf * 16 + quad * 4] = pk;
      }
      // wave-private: compiler inserts lgkmcnt wait before re-read
#pragma unroll
      for (int p = 0; p < 4; ++p) {
        const int u = p * 64 + lane;          // 256 x 16B units
        const int dl = u >> 4, ch = (u & 15) * 8;
        short8 vv = *(const short8*)&Wn[(size_t)dl * 128 + ch];
        *(short8*)&Vth[(bh * 64 + d0 + dl) * 1024 + i0l + ch] = vv;
      }
    }
  }
}

// ---------------- out GEMM  out[4096,1024] = Aoh @ Wo^T + b_o ----------------
// 128x64 tile, BK=64 two-plane -> 512 blocks. 4 waves stacked in M.
__global__ __launch_bounds__(256)
void gemm_out(const unsigned short* __restrict__ A,   // 4096 x 1024
              const unsigned short* __restrict__ Bm,  // 1024 x 1024
              const float* __restrict__ bias,
              float* __restrict__ outf) {
  __shared__ unsigned short As[2][128 * 32];  // 16 KB
  __shared__ unsigned short Bs[2][64 * 32];   // 8 KB
  const int tid  = threadIdx.x;
  const int lane = tid & 63, wave = tid >> 6;
  const int quad = lane >> 4, l15 = lane & 15;
  const int m0 = blockIdx.y * 128, n0 = blockIdx.x * 64;
  const int K = 1024;

  const f32x4 vzero = {0.f, 0.f, 0.f, 0.f};
  f32x4 acc[2][4];
#pragma unroll
  for (int i = 0; i < 2; ++i)
#pragma unroll
    for (int j = 0; j < 4; ++j) acc[i][j] = vzero;

  for (int k0 = 0; k0 < K; k0 += 64) {
    __syncthreads();
#pragma unroll
    for (int j = 0; j < 4; ++j) {       // A: 1024 units
      int u = j * 256 + tid;
      int half = u >> 9, row = (u >> 2) & 127, c = (u & 3) * 8 + half * 32;
      gload_lds16(A + (size_t)(m0 + row) * K + k0 + c, (char*)&As[0][0] + (size_t)u * 16);
    }
#pragma unroll
    for (int j = 0; j < 2; ++j) {       // B: 512 units
      int u = j * 256 + tid;
      int half = u >> 8, row = (u >> 2) & 63, c = (u & 3) * 8 + half * 32;
      gload_lds16(Bm + (size_t)(n0 + row) * K + k0 + c, (char*)&Bs[0][0] + (size_t)u * 16);
    }
    __syncthreads();

#pragma unroll
    for (int ks = 0; ks < 2; ++ks) {
      short8 af[2], bfv[4];
#pragma unroll
      for (int mt = 0; mt < 2; ++mt)
        af[mt] = *(const short8*)&As[ks][(wave * 32 + mt * 16 + l15) * 32 + quad * 8];
#pragma unroll
      for (int nt = 0; nt < 4; ++nt)
        bfv[nt] = *(const short8*)&Bs[ks][(nt * 16 + l15) * 32 + quad * 8];
#pragma unroll
      for (int mt = 0; mt < 2; ++mt)
#pragma unroll
        for (int nt = 0; nt < 4; ++nt)
          acc[mt][nt] = MFMA_BF16(af[mt], bfv[nt], acc[mt][nt]);
    }
  }

#pragma unroll
  for (int mt = 0; mt < 2; ++mt)
#pragma unroll
    for (int nt = 0; nt < 4; ++nt)
#pragma unroll
      for (int r = 0; r < 4; ++r) {
        const int gm = m0 + wave * 32 + mt * 16 + quad * 4 + r;
        const int gn = n0 + nt * 16 + l15;
        outf[(size_t)gm * 1024 + gn] = acc[mt][nt][r] + bias[gn];
      }
}

// ---------------- flash attention, LDS-staged K/V, prefetch ----------------
// grid (64 bh, 8 qblocks of 128), 256 threads. Wave owns 32 query rows.
// Q pre-scaled by log2(e)/8; no-max softmax (exp2 cannot overflow here).
__global__ __launch_bounds__(256)
void attn_kernel(const unsigned short* __restrict__ Q,
                 const unsigned short* __restrict__ Kp,
                 const unsigned short* __restrict__ Vt,
                 unsigned short* __restrict__ Ao) {
  __shared__ unsigned short Ks[2][2][64 * 32];  // [buf][half][key][32]
  __shared__ unsigned short Vs[2][2][64 * 32];  // [buf][half][d][32]
  __shared__ unsigned short Plds[4][32 * 72];   // per-wave P transpose
  const int tid  = threadIdx.x;
  const int lane = tid & 63, wave = tid >> 6;
  const int quad = lane >> 4, l15 = lane & 15;
  const int bh = blockIdx.x;
  const int qb = blockIdx.y;
  const size_t base  = (size_t)bh * (kL * 64);
  const size_t vbase = (size_t)bh * (64 * kL);
  const int i0 = qb * 128 + wave * 32;

  short8 qf[2][2];
#pragma unroll
  for (int mt = 0; mt < 2; ++mt)
#pragma unroll
    for (int ks = 0; ks < 2; ++ks)
      qf[mt][ks] = *(const short8*)
          &Q[base + (size_t)(i0 + mt * 16 + l15) * 64 + ks * 32 + quad * 8];

  auto stage = [&](int buf, int kb) {
#pragma unroll
    for (int j = 0; j < 2; ++j) {
      int u = j * 256 + tid;
      int half = u >> 8, row = (u >> 2) & 63, c = (u & 3) * 8;
      gload_lds16(Kp + base + (size_t)(kb * 64 + row) * 64 + half * 32 + c,
                  (char*)&Ks[buf][0][0] + (size_t)u * 16);
      gload_lds16(Vt + vbase + (size_t)row * kL + kb * 64 + half * 32 + c,
                  (char*)&Vs[buf][0][0] + (size_t)u * 16);
    }
  };

  const f32x4 vzero = {0.f, 0.f, 0.f, 0.f};
  f32x4 of[2][4];
#pragma unroll
  for (int mt = 0; mt < 2; ++mt)
#pragma unroll
    for (int dt = 0; dt < 4; ++dt) of[mt][dt] = vzero;
  float lsum[2][4] = {{0.f, 0.f, 0.f, 0.f}, {0.f, 0.f, 0.f, 0.f}};

  unsigned short* Pw = Plds[wave];

  stage(0, 0);
  __syncthreads();

  for (int kb = 0; kb < 16; ++kb) {
    const int cur = kb & 1, nxt = cur ^ 1;
    if (kb < 15) stage(nxt, kb + 1);

    short8 kf[4][2];
#pragma unroll
    for (int nt = 0; nt < 4; ++nt)
#pragma unroll
      for (int ks = 0; ks < 2; ++ks)
        kf[nt][ks] = *(const short8*)&Ks[cur][ks][(nt * 16 + l15) * 32 + quad * 8];
    f32x4 sf[2][4];
#pragma unroll
    for (int mt = 0; mt < 2; ++mt)
#pragma unroll
      for (int nt = 0; nt < 4; ++nt) {
        sf[mt][nt] = MFMA_BF16(qf[mt][0], kf[nt][0], vzero);
        sf[mt][nt] = MFMA_BF16(qf[mt][1], kf[nt][1], sf[mt][nt]);
      }

#pragma unroll
    for (int mt = 0; mt < 2; ++mt)
#pragma unroll
      for (int nt = 0; nt < 4; ++nt)
#pragma unroll
        for (int r = 0; r < 4; ++r) {
          float p = __builtin_amdgcn_exp2f(sf[mt][nt][r]);
          lsum[mt][r] += p;
          union { float f; uint32_t u; } c; c.f = p;
          Pw[(mt * 16 + quad * 4 + r) * 72 + nt * 16 + l15] =
              (unsigned short)((c.u + 0x8000u) >> 16);
        }
    short8 pf[2][2];
#pragma unroll
    for (int mt = 0; mt < 2; ++mt)
#pragma unroll
      for (int ks = 0; ks < 2; ++ks)
        pf[mt][ks] = *(const short8*)&Pw[(mt * 16 + l15) * 72 + ks * 32 + quad * 8];

    short8 vf[4][2];
#pragma unroll
    for (int dt = 0; dt < 4; ++dt)
#pragma unroll
      for (int ks = 0; ks < 2; ++ks)
        vf[dt][ks] = *(const short8*)&Vs[cur][ks][(dt * 16 + l15) * 32 + quad * 8];
#pragma unroll
    for (int mt = 0; mt < 2; ++mt)
#pragma unroll
      for (int dt = 0; dt < 4; ++dt) {
        of[mt][dt] = MFMA_BF16(pf[mt][0], vf[dt][0], of[mt][dt]);
        of[mt][dt] = MFMA_BF16(pf[mt][1], vf[dt][1], of[mt][dt]);
      }

    __syncthreads();
  }

#pragma unroll
  for (int mask = 1; mask < 16; mask <<= 1)
#pragma unroll
    for (int mt = 0; mt < 2; ++mt)
#pragma unroll
      for (int r = 0; r < 4; ++r)
        lsum[mt][r] += __shfl_xor(lsum[mt][r], mask);
  float rl[2][4];
#pragma unroll
  for (int mt = 0; mt < 2; ++mt)
#pragma unroll
    for (int r = 0; r < 4; ++r) rl[mt][r] = __builtin_amdgcn_rcpf(lsum[mt][r]);

  const int b = bh >> 4, h = bh & 15;
#pragma unroll
  for (int mt = 0; mt < 2; ++mt)
#pragma unroll
    for (int dt = 0; dt < 4; ++dt)
#pragma unroll
      for (int r = 0; r < 4; ++r) {
        const int ig = i0 + mt * 16 + quad * 4 + r;
        float v = of[mt][dt][r] * rl[mt][r];
        Ao[((size_t)(b * 1024 + ig)) * 1024 + h * 64 + dt * 16 + l15] = f32_to_bf16(v);
      }
}

// ---------------------------------------------------------------------------
extern "C" void kernel_launch(void* const* d_in, const int* in_sizes, int n_in,
                              void* d_out, int out_size, void* d_ws, size_t ws_size,
                              hipStream_t stream) {
  const float* x   = (const float*)d_in[0];
  const float* W_q = (const float*)d_in[1];
  const float* b_q = (const float*)d_in[2];
  const float* W_k = (const float*)d_in[3];
  const float* b_k = (const float*)d_in[4];
  const float* W_v = (const float*)d_in[5];
  const float* b_v = (const float*)d_in[6];
  const float* W_o = (const float*)d_in[7];
  const float* b_o = (const float*)d_in[8];
  const float* Er  = (const float*)d_in[9];
  float* out = (float*)d_out;

  char* ws = (char*)d_ws;
  unsigned short* xb   = (unsigned short*)(ws + (size_t)0);          // 8 MB
  unsigned short* Wcat = (unsigned short*)(ws + ((size_t)8  << 20)); // 6 MB (Wq|Wk|Wv)
  unsigned short* Wob  = (unsigned short*)(ws + ((size_t)14 << 20)); // 2 MB
  unsigned short* Qh   = (unsigned short*)(ws + ((size_t)16 << 20)); // 8 MB [bh][i][d]
  unsigned short* Kh   = (unsigned short*)(ws + ((size_t)24 << 20)); // 8 MB [bh][i][d]
  unsigned short* Vth  = (unsigned short*)(ws + ((size_t)32 << 20)); // 8 MB [bh][d][i]
  unsigned short* Aoh  = (unsigned short*)(ws + ((size_t)40 << 20)); // 8 MB [b*L][D]

  cast_all<<<8192, 256, 0, stream>>>(x, W_q, W_k, W_v, W_o, xb, Wcat, Wob);

  gemm_qkv<<<256, 512, 0, stream>>>(
      xb, Wcat, b_q, b_k, b_v, Er, Qh, Kh, Vth);

  attn_kernel<<<dim3(kB * kH, kL / 128), 256, 0, stream>>>(Qh, Kh, Vth, Aoh);

  gemm_out<<<dim3(16, 32), 256, 0, stream>>>(Aoh, Wob, b_o, out);
}

// Round 4
// 172.119 us; speedup vs baseline: 1.0931x; 1.0072x over previous
//
#include <hip/hip_runtime.h>
#include <cstdint>
#include <cstddef>

// ---------------------------------------------------------------------------
// RelativePositionMultiHeadAttention, B=4 L=1024 D=1024 H=16 dk=64
// Identity: BD[...,L-1:][b,h,i,j] = Q[b,h,i] . Er[4999-j]
//  => scores = Q @ (K + Er_flip)^T / 8  -> plain softmax attention.
// R10 = R9 with one bug fixed: gemm_out B-plane k-half stride is 4096 B
//     (64 rows x 32 elems x 2B), not 8192 (that's A's). R9 read ks*8192,
//     pulling the second k-half of B from the wrong LDS region -> absmax 5.7.
// R9 (gemm_qkv frozen as control = R8):
//  * attn: swapped QK^T (S^T = mfma(K,Q)) so each lane owns one query row's
//    P slice -> P-transpose becomes 8 ds_write_b64 (was 32 ds_write_b16);
//    lsum is lane-local, one shfl-reduce at the end.
//  * gemm_out: true double-buffer, counted vmcnt(6) + raw s_barrier, XOR
//    swizzle on both planes.
// ---------------------------------------------------------------------------

typedef __attribute__((ext_vector_type(8))) short short8;   // 8 x bf16 (4 VGPR)
typedef __attribute__((ext_vector_type(4))) float f32x4;    // 4 x f32

#define MFMA_BF16(a, b, c) __builtin_amdgcn_mfma_f32_16x16x32_bf16((a), (b), (c), 0, 0, 0)

constexpr int kB = 4, kL = 1024, kD = 1024, kH = 16;
constexpr int kBL = kB * kL;   // 4096
constexpr float kScale = 0.125f * 1.44269504088896340736f;  // log2(e)/sqrt(dk)

static __device__ __forceinline__ unsigned short f32_to_bf16(float f) {
  union { float f; uint32_t u; } c; c.f = f;
  uint32_t u = c.u + 0x7fffu + ((c.u >> 16) & 1u);  // RNE
  return (unsigned short)(u >> 16);
}

static __device__ __forceinline__ uint32_t pack_bf16x2(float a, float b) {
  union { float f; uint32_t u; } ca, cb; ca.f = a; cb.f = b;
  return ((ca.u + 0x8000u) >> 16) | ((cb.u + 0x8000u) & 0xffff0000u);
}

static __device__ __forceinline__ void gload_lds16(const void* g, void* l) {
  __builtin_amdgcn_global_load_lds(
      (const __attribute__((address_space(1))) void*)g,
      (__attribute__((address_space(3))) void*)l, 16, 0, 0);
}

// ---------------- single fused cast: x, Wq, Wk, Wv, Wo -> bf16 ----------------
__global__ __launch_bounds__(256)
void cast_all(const float* __restrict__ x,  const float* __restrict__ Wq,
              const float* __restrict__ Wk, const float* __restrict__ Wv,
              const float* __restrict__ Wo,
              unsigned short* __restrict__ xb, unsigned short* __restrict__ Wcat,
              unsigned short* __restrict__ Wob) {
  int i = blockIdx.x * blockDim.x + threadIdx.x;
  const float* src;
  ushort4* dst;
  int off;
  if (i < 1048576) {
    src = x; dst = reinterpret_cast<ushort4*>(xb); off = i;
  } else {
    int j = i - 1048576;
    int seg = j >> 18;          // 0..3
    off = j & 262143;
    if (seg == 0)      { src = Wq; dst = reinterpret_cast<ushort4*>(Wcat); }
    else if (seg == 1) { src = Wk; dst = reinterpret_cast<ushort4*>(Wcat) + 262144; }
    else if (seg == 2) { src = Wv; dst = reinterpret_cast<ushort4*>(Wcat) + 524288; }
    else               { src = Wo; dst = reinterpret_cast<ushort4*>(Wob); }
  }
  float4 v = reinterpret_cast<const float4*>(src)[off];
  ushort4 o;
  o.x = f32_to_bf16(v.x); o.y = f32_to_bf16(v.y);
  o.z = f32_to_bf16(v.z); o.w = f32_to_bf16(v.w);
  dst[off] = o;
}

// ---------------- fused QKV GEMM  [4096 x 3072] = xb @ Wcat^T ----------------
// (unchanged from R8 -- control)
__global__ __launch_bounds__(512, 2)
void gemm_qkv(const unsigned short* __restrict__ A,   // 4096 x 1024 bf16
              const unsigned short* __restrict__ Bm,  // 3072 x 1024 bf16
              const float* __restrict__ bq, const float* __restrict__ bk,
              const float* __restrict__ bv,
              const float* __restrict__ Er,           // 5000x64 f32
              unsigned short* __restrict__ Qh, unsigned short* __restrict__ Kh,
              unsigned short* __restrict__ Vth) {
  __shared__ __align__(16) char smem[114688];
  const int tid  = threadIdx.x;
  const int lane = tid & 63, wave = tid >> 6;
  const int quad = lane >> 4, l15 = lane & 15;
  const int wr = wave >> 2, wc = wave & 3;          // 2 x 4 wave grid

  const int bid = blockIdx.x;
  const int xcd = bid & 7, idx = bid >> 3;          // idx 0..31
  const int m0 = ((xcd >> 1) * 4 + (idx >> 3)) * 256;
  const int n0 = ((xcd & 1) * 8 + (idx & 7)) * 192;

  const int aoff = (l15 >> 1) * 128 + (l15 & 1) * 64 +
                   ((quad * 16) ^ (((l15 >> 1) & 3) << 4)) + wr * 8192;
  const int b_lane = (quad * 16) ^ ((l15 & 7) << 4);
  const int boff = (wc * 48 + l15) * 128 + b_lane;   // + nf*2048, ^ kh*64

  int srowA[2], scolA[2];
#pragma unroll
  for (int j = 0; j < 2; ++j) {
    int poff = (j * 512 + tid) * 16;
    int L = poff ^ (((poff >> 7) & 3) << 4);
    srowA[j] = ((L >> 7) << 1) | ((L >> 6) & 1);
    scolA[j] = (L & 63) >> 1;                        // elem 0..31
  }
  int srowB[3], scolB[3];
#pragma unroll
  for (int j = 0; j < 3; ++j) {
    int poff = (j * 512 + tid) * 16;
    int L = poff ^ (((poff >> 7) & 7) << 4);
    srowB[j] = L >> 7;                               // 0..191
    scolB[j] = (L & 127) >> 1;                       // elem 0..63
  }

  auto stageA = [&](int kh, int tt) {                // 2 loads/thread
    char* dst = smem + (tt & 1) * 32768 + kh * 16384 + tid * 16;
    const int kc = tt * 64 + kh * 32;
#pragma unroll
    for (int j = 0; j < 2; ++j)
      gload_lds16(A + (size_t)(m0 + srowA[j]) * 1024 + kc + scolA[j],
                  dst + j * 8192);
  };
  auto stageB = [&](int tt) {                        // 3 loads/thread
    char* dst = smem + 65536 + (tt & 1) * 24576 + tid * 16;
    const int kc = tt * 64;
#pragma unroll
    for (int j = 0; j < 3; ++j)
      gload_lds16(Bm + (size_t)(n0 + srowB[j]) * 1024 + kc + scolB[j],
                  dst + j * 8192);
  };

  const f32x4 vzero = {0.f, 0.f, 0.f, 0.f};
  f32x4 acc[8][3];
#pragma unroll
  for (int i = 0; i < 8; ++i)
#pragma unroll
    for (int j = 0; j < 3; ++j) acc[i][j] = vzero;

  stageA(0, 0); stageB(0); stageA(1, 0); stageA(0, 1);
  asm volatile("s_waitcnt vmcnt(4)" ::: "memory");
  __builtin_amdgcn_s_barrier();

#define LDA(KH, MB) do {                                                      \
    _Pragma("unroll")                                                         \
    for (int f_ = 0; f_ < 4; ++f_)                                            \
      af[f_] = *(const short8*)(RA + (KH) * 16384 + aoff + ((MB) + f_) * 1024); \
  } while (0)
#define LDB(KH) do {                                                          \
    _Pragma("unroll")                                                         \
    for (int n_ = 0; n_ < 3; ++n_)                                            \
      bf[n_] = *(const short8*)(RB + ((boff + n_ * 2048) ^ ((KH) * 64)));     \
  } while (0)
#define BARA() do {                                                           \
    __builtin_amdgcn_s_barrier();                                             \
    asm volatile("s_waitcnt lgkmcnt(0)" ::: "memory");                        \
    __builtin_amdgcn_sched_barrier(0);                                        \
  } while (0)
#define MFMA_12(MB) do {                                                      \
    __builtin_amdgcn_s_setprio(1);                                            \
    _Pragma("unroll")                                                         \
    for (int mq_ = 0; mq_ < 4; ++mq_) {                                       \
      _Pragma("unroll")                                                       \
      for (int nq_ = 0; nq_ < 3; ++nq_)                                       \
        acc[(MB) + mq_][nq_] =                                                \
            MFMA_BF16(af[mq_], bf[nq_], acc[(MB) + mq_][nq_]);                \
    }                                                                         \
    __builtin_amdgcn_s_setprio(0);                                            \
  } while (0)

  for (int t = 0; t < 16; ++t) {
    const char* RA = smem + (t & 1) * 32768;
    const char* RB = smem + 65536 + (t & 1) * 24576;
    short8 af[4], bf[3];
    LDA(0, 0); LDB(0);
    if (t + 1 < 16) stageB(t + 1);
    BARA(); MFMA_12(0);
    __builtin_amdgcn_s_barrier();
    LDA(0, 4);
    if (t + 1 < 16) stageA(1, t + 1);
    BARA(); MFMA_12(4);
    if (t < 15) asm volatile("s_waitcnt vmcnt(7)" ::: "memory");
    else        asm volatile("s_waitcnt vmcnt(0)" ::: "memory");
    __builtin_amdgcn_s_barrier();
    LDA(1, 0); LDB(1);
    if (t + 2 < 16) stageA(0, t + 2);
    BARA(); MFMA_12(0);
    __builtin_amdgcn_s_barrier();
    LDA(1, 4);
    BARA(); MFMA_12(4);
    if (t < 14)       asm volatile("s_waitcnt vmcnt(4)" ::: "memory");
    else if (t == 14) asm volatile("s_waitcnt vmcnt(2)" ::: "memory");
    else              asm volatile("s_waitcnt vmcnt(0)" ::: "memory");
    __builtin_amdgcn_s_barrier();
  }

#undef LDA
#undef LDB
#undef BARA
#undef MFMA_12

  __syncthreads();                           // before LDS arena reuse (uncond.)
  const int gmb = m0 + wr * 128;
  const int bb  = gmb >> 10, i0l = gmb & 1023;
  unsigned short* Wv = (unsigned short*)smem + (size_t)wave * 6144;  // 12 KiB

#pragma unroll
  for (int nf = 0; nf < 3; ++nf) {
    const int n    = n0 + wc * 48 + nf * 16;  // 16-aligned global col
    const int wsel = n >> 10;                 // 0=Q 1=K 2=V
    const int nin  = n & 1023;
    const int hh   = nin >> 6, d0 = nin & 63; // d0 in {0,16,32,48}
    const size_t bh = (size_t)(bb * 16 + hh);

    if (wsel == 0) {
#pragma unroll
      for (int mf = 0; mf < 8; ++mf)
#pragma unroll
        for (int r = 0; r < 4; ++r) {
          const int i = i0l + mf * 16 + quad * 4 + r;
          float v = (acc[mf][nf][r] + bq[nin + l15]) * kScale;  // fold scale
          Qh[(bh * 1024 + i) * 64 + d0 + l15] = f32_to_bf16(v);
        }
    } else if (wsel == 1) {
#pragma unroll
      for (int mf = 0; mf < 8; ++mf)
#pragma unroll
        for (int r = 0; r < 4; ++r) {
          const int i = i0l + mf * 16 + quad * 4 + r;
          float v = acc[mf][nf][r] + bk[nin + l15] +
                    Er[(size_t)(4999 - i) * 64 + d0 + l15];
          Kh[(bh * 1024 + i) * 64 + d0 + l15] = f32_to_bf16(v);
        }
    } else {
      unsigned short* Wn = Wv + nf * 2048;    // [16][128]
#pragma unroll
      for (int mf = 0; mf < 8; ++mf) {
        ushort4 pk;
        pk.x = f32_to_bf16(acc[mf][nf][0] + bv[nin + l15]);
        pk.y = f32_to_bf16(acc[mf][nf][1] + bv[nin + l15]);
        pk.z = f32_to_bf16(acc[mf][nf][2] + bv[nin + l15]);
        pk.w = f32_to_bf16(acc[mf][nf][3] + bv[nin + l15]);
        *(ushort4*)&Wn[(size_t)l15 * 128 + mf * 16 + quad * 4] = pk;
      }
#pragma unroll
      for (int p = 0; p < 4; ++p) {
        const int u = p * 64 + lane;          // 256 x 16B units
        const int dl = u >> 4, ch = (u & 15) * 8;
        short8 vv = *(const short8*)&Wn[(size_t)dl * 128 + ch];
        *(short8*)&Vth[(bh * 64 + d0 + dl) * 1024 + i0l + ch] = vv;
      }
    }
  }
}

// ---------------- out GEMM  out[4096,1024] = Aoh @ Wo^T + b_o ----------------
// 128x64 tile, BK=64, true double-buffer (48 KB), counted vmcnt + raw
// s_barrier so next-tile global_load_lds stays in flight across the barrier.
// Both planes use the 2-rows-per-128B-line XOR swizzle (conflict-free reads).
// A khalf stride = 8192 B (128 rows), B khalf stride = 4096 B (64 rows).
__global__ __launch_bounds__(256)
void gemm_out(const unsigned short* __restrict__ A,   // 4096 x 1024
              const unsigned short* __restrict__ Bm,  // 1024 x 1024
              const float* __restrict__ bias,
              float* __restrict__ outf) {
  __shared__ __align__(16) char smem[49152];   // [buf: A 16KB | B 8KB] x2
  const int tid  = threadIdx.x;
  const int lane = tid & 63, wave = tid >> 6;
  const int quad = lane >> 4, l15 = lane & 15;
  const int m0 = blockIdx.y * 128, n0 = blockIdx.x * 64;

  // frag-read lane constant (2 rows per 128B line, byte ^= (line&3)<<4):
  const int afo = (l15 >> 1) * 128 + (l15 & 1) * 64 +
                  ((quad * 16) ^ (((l15 >> 1) & 3) << 4));

  // staging decoders (phys -> logical row/col inside one [128|64]x32 khalf)
  int arow[4], acol[4], akh[4];
#pragma unroll
  for (int j = 0; j < 4; ++j) {
    int u = j * 256 + tid;                 // 0..1023 (A: 1024 x 16B units)
    akh[j] = u >> 9;
    int poff = (u & 511) * 16;
    int L = poff ^ (((poff >> 7) & 3) << 4);
    arow[j] = ((L >> 7) << 1) | ((L >> 6) & 1);     // 0..127
    acol[j] = (L & 63) >> 1;                        // elem 0..31
  }
  int brow[2], bcol[2], bkh[2];
#pragma unroll
  for (int j = 0; j < 2; ++j) {
    int u = j * 256 + tid;                 // 0..511 (B: 512 x 16B units)
    bkh[j] = u >> 8;
    int poff = (u & 255) * 16;
    int L = poff ^ (((poff >> 7) & 3) << 4);
    brow[j] = ((L >> 7) << 1) | ((L >> 6) & 1);     // 0..63
    bcol[j] = (L & 63) >> 1;
  }

  auto stageG = [&](int buf, int t) {      // 6 loads/thread
    char* base = smem + buf * 24576;
    const int kc = t * 64;
#pragma unroll
    for (int j = 0; j < 4; ++j) {
      int u = j * 256 + tid;
      gload_lds16(A + (size_t)(m0 + arow[j]) * 1024 + kc + akh[j] * 32 + acol[j],
                  base + u * 16);
    }
#pragma unroll
    for (int j = 0; j < 2; ++j) {
      int u = j * 256 + tid;
      gload_lds16(Bm + (size_t)(n0 + brow[j]) * 1024 + kc + bkh[j] * 32 + bcol[j],
                  base + 16384 + u * 16);
    }
  };

  const f32x4 vzero = {0.f, 0.f, 0.f, 0.f};
  f32x4 acc[2][4];
#pragma unroll
  for (int i = 0; i < 2; ++i)
#pragma unroll
    for (int j = 0; j < 4; ++j) acc[i][j] = vzero;

  stageG(0, 0);
  for (int t = 0; t < 16; ++t) {
    const int cur = t & 1;
    if (t < 15) stageG(cur ^ 1, t + 1);
    if (t < 15) asm volatile("s_waitcnt vmcnt(6)" ::: "memory");
    else        asm volatile("s_waitcnt vmcnt(0)" ::: "memory");
    __builtin_amdgcn_s_barrier();
    __builtin_amdgcn_sched_barrier(0);
    const char* Ab = smem + cur * 24576;
    const char* Bb = Ab + 16384;
#pragma unroll
    for (int ks = 0; ks < 2; ++ks) {
      short8 af[2], bfv[4];
#pragma unroll
      for (int mt = 0; mt < 2; ++mt)
        af[mt] = *(const short8*)(Ab + ks * 8192 + wave * 2048 + mt * 1024 + afo);
#pragma unroll
      for (int nt = 0; nt < 4; ++nt)
        bfv[nt] = *(const short8*)(Bb + ks * 4096 + nt * 1024 + afo);
#pragma unroll
      for (int mt = 0; mt < 2; ++mt)
#pragma unroll
        for (int nt = 0; nt < 4; ++nt)
          acc[mt][nt] = MFMA_BF16(af[mt], bfv[nt], acc[mt][nt]);
    }
    __builtin_amdgcn_s_barrier();
    __builtin_amdgcn_sched_barrier(0);
  }

#pragma unroll
  for (int mt = 0; mt < 2; ++mt)
#pragma unroll
    for (int nt = 0; nt < 4; ++nt)
#pragma unroll
      for (int r = 0; r < 4; ++r) {
        const int gm = m0 + wave * 32 + mt * 16 + quad * 4 + r;
        const int gn = n0 + nt * 16 + l15;
        outf[(size_t)gm * 1024 + gn] = acc[mt][nt][r] + bias[gn];
      }
}

// ---------------- flash attention, LDS-staged K/V, prefetch ----------------
// grid (64 bh, 8 qblocks of 128), 256 threads. Wave owns 32 query rows.
// Q pre-scaled by log2(e)/8; no-max softmax (exp2 cannot overflow here).
// Swapped QK^T: sf = mfma(K,Q) -> lane holds P[i=mt*16+l15][key=16nt+4q+r];
// P-store is 8 ds_write_b64/iter; lsum lane-local, reduced once at the end.
__global__ __launch_bounds__(256)
void attn_kernel(const unsigned short* __restrict__ Q,
                 const unsigned short* __restrict__ Kp,
                 const unsigned short* __restrict__ Vt,
                 unsigned short* __restrict__ Ao) {
  __shared__ unsigned short Ks[2][2][64 * 32];  // [buf][half][key][32]
  __shared__ unsigned short Vs[2][2][64 * 32];  // [buf][half][d][32]
  __shared__ unsigned short Plds[4][32 * 72];   // per-wave P rows
  const int tid  = threadIdx.x;
  const int lane = tid & 63, wave = tid >> 6;
  const int quad = lane >> 4, l15 = lane & 15;
  const int bh = blockIdx.x;
  const int qb = blockIdx.y;
  const size_t base  = (size_t)bh * (kL * 64);
  const size_t vbase = (size_t)bh * (64 * kL);
  const int i0 = qb * 128 + wave * 32;

  short8 qf[2][2];
#pragma unroll
  for (int mt = 0; mt < 2; ++mt)
#pragma unroll
    for (int ks = 0; ks < 2; ++ks)
      qf[mt][ks] = *(const short8*)
          &Q[base + (size_t)(i0 + mt * 16 + l15) * 64 + ks * 32 + quad * 8];

  auto stage = [&](int buf, int kb) {
#pragma unroll
    for (int j = 0; j < 2; ++j) {
      int u = j * 256 + tid;
      int half = u >> 8, row = (u >> 2) & 63, c = (u & 3) * 8;
      gload_lds16(Kp + base + (size_t)(kb * 64 + row) * 64 + half * 32 + c,
                  (char*)&Ks[buf][0][0] + (size_t)u * 16);
      gload_lds16(Vt + vbase + (size_t)row * kL + kb * 64 + half * 32 + c,
                  (char*)&Vs[buf][0][0] + (size_t)u * 16);
    }
  };

  const f32x4 vzero = {0.f, 0.f, 0.f, 0.f};
  f32x4 of[2][4];
#pragma unroll
  for (int mt = 0; mt < 2; ++mt)
#pragma unroll
    for (int dt = 0; dt < 4; ++dt) of[mt][dt] = vzero;
  float lsum[2] = {0.f, 0.f};

  unsigned short* Pw = Plds[wave];

  stage(0, 0);
  __syncthreads();

  for (int kb = 0; kb < 16; ++kb) {
    const int cur = kb & 1, nxt = cur ^ 1;
    if (kb < 15) stage(nxt, kb + 1);

    short8 kf[4][2];
#pragma unroll
    for (int nt = 0; nt < 4; ++nt)
#pragma unroll
      for (int ks = 0; ks < 2; ++ks)
        kf[nt][ks] = *(const short8*)&Ks[cur][ks][(nt * 16 + l15) * 32 + quad * 8];
    // S^T = K . Q^T : lane holds P[i = mt*16+l15][key = nt*16 + quad*4 + r]
    f32x4 sf[2][4];
#pragma unroll
    for (int mt = 0; mt < 2; ++mt)
#pragma unroll
      for (int nt = 0; nt < 4; ++nt) {
        sf[mt][nt] = MFMA_BF16(kf[nt][0], qf[mt][0], vzero);
        sf[mt][nt] = MFMA_BF16(kf[nt][1], qf[mt][1], sf[mt][nt]);
      }

#pragma unroll
    for (int mt = 0; mt < 2; ++mt)
#pragma unroll
      for (int nt = 0; nt < 4; ++nt) {
        float p0 = __builtin_amdgcn_exp2f(sf[mt][nt][0]);
        float p1 = __builtin_amdgcn_exp2f(sf[mt][nt][1]);
        float p2 = __builtin_amdgcn_exp2f(sf[mt][nt][2]);
        float p3 = __builtin_amdgcn_exp2f(sf[mt][nt][3]);
        lsum[mt] += (p0 + p1) + (p2 + p3);
        uint2 w;
        w.x = pack_bf16x2(p0, p1);
        w.y = pack_bf16x2(p2, p3);
        *(uint2*)&Pw[(mt * 16 + l15) * 72 + nt * 16 + quad * 4] = w;
      }
    short8 pf[2][2];
#pragma unroll
    for (int mt = 0; mt < 2; ++mt)
#pragma unroll
      for (int ks = 0; ks < 2; ++ks)
        pf[mt][ks] = *(const short8*)&Pw[(mt * 16 + l15) * 72 + ks * 32 + quad * 8];

    short8 vf[4][2];
#pragma unroll
    for (int dt = 0; dt < 4; ++dt)
#pragma unroll
      for (int ks = 0; ks < 2; ++ks)
        vf[dt][ks] = *(const short8*)&Vs[cur][ks][(dt * 16 + l15) * 32 + quad * 8];
#pragma unroll
    for (int mt = 0; mt < 2; ++mt)
#pragma unroll
      for (int dt = 0; dt < 4; ++dt) {
        of[mt][dt] = MFMA_BF16(pf[mt][0], vf[dt][0], of[mt][dt]);
        of[mt][dt] = MFMA_BF16(pf[mt][1], vf[dt][1], of[mt][dt]);
      }

    __syncthreads();
  }

  // row-sum finalize: lane l15 holds full sum for row i = mt*16+l15 after
  // cross-quad reduce; broadcast to (quad,r) consumers.
  float rl[2][4];
#pragma unroll
  for (int mt = 0; mt < 2; ++mt) {
    float s = lsum[mt];
    s += __shfl_xor(s, 16);
    s += __shfl_xor(s, 32);
#pragma unroll
    for (int r = 0; r < 4; ++r)
      rl[mt][r] = __builtin_amdgcn_rcpf(__shfl(s, quad * 4 + r));
  }

  const int b = bh >> 4, h = bh & 15;
#pragma unroll
  for (int mt = 0; mt < 2; ++mt)
#pragma unroll
    for (int dt = 0; dt < 4; ++dt)
#pragma unroll
      for (int r = 0; r < 4; ++r) {
        const int ig = i0 + mt * 16 + quad * 4 + r;
        float v = of[mt][dt][r] * rl[mt][r];
        Ao[((size_t)(b * 1024 + ig)) * 1024 + h * 64 + dt * 16 + l15] = f32_to_bf16(v);
      }
}

// ---------------------------------------------------------------------------
extern "C" void kernel_launch(void* const* d_in, const int* in_sizes, int n_in,
                              void* d_out, int out_size, void* d_ws, size_t ws_size,
                              hipStream_t stream) {
  const float* x   = (const float*)d_in[0];
  const float* W_q = (const float*)d_in[1];
  const float* b_q = (const float*)d_in[2];
  const float* W_k = (const float*)d_in[3];
  const float* b_k = (const float*)d_in[4];
  const float* W_v = (const float*)d_in[5];
  const float* b_v = (const float*)d_in[6];
  const float* W_o = (const float*)d_in[7];
  const float* b_o = (const float*)d_in[8];
  const float* Er  = (const float*)d_in[9];
  float* out = (float*)d_out;

  char* ws = (char*)d_ws;
  unsigned short* xb   = (unsigned short*)(ws + (size_t)0);          // 8 MB
  unsigned short* Wcat = (unsigned short*)(ws + ((size_t)8  << 20)); // 6 MB (Wq|Wk|Wv)
  unsigned short* Wob  = (unsigned short*)(ws + ((size_t)14 << 20)); // 2 MB
  unsigned short* Qh   = (unsigned short*)(ws + ((size_t)16 << 20)); // 8 MB [bh][i][d]
  unsigned short* Kh   = (unsigned short*)(ws + ((size_t)24 << 20)); // 8 MB [bh][i][d]
  unsigned short* Vth  = (unsigned short*)(ws + ((size_t)32 << 20)); // 8 MB [bh][d][i]
  unsigned short* Aoh  = (unsigned short*)(ws + ((size_t)40 << 20)); // 8 MB [b*L][D]

  cast_all<<<8192, 256, 0, stream>>>(x, W_q, W_k, W_v, W_o, xb, Wcat, Wob);

  gemm_qkv<<<256, 512, 0, stream>>>(
      xb, Wcat, b_q, b_k, b_v, Er, Qh, Kh, Vth);

  attn_kernel<<<dim3(kB * kH, kL / 128), 256, 0, stream>>>(Qh, Kh, Vth, Aoh);

  gemm_out<<<dim3(16, 32), 256, 0, stream>>>(Aoh, Wob, b_o, out);
}